// Round 11
// baseline (44.206 us; speedup 1.0000x reference)
//
#include <hip/hip_runtime.h>

#define TPB 256
#define ROWS_PER_B 128   // one block = 128 rows; 2 threads per row in phase B

// y is exactly 0.0f or 1.0f; -(y*log(p) + (1-y)*log1p(-p)) reduces to a select.
__device__ __forceinline__ float bce1(float p, float y) {
    return (y > 0.5f) ? -__logf(p) : -__logf(1.0f - p);
}
__device__ __forceinline__ float bce4(float4 p, float4 y) {
    return bce1(p.x, y.x) + bce1(p.y, y.y) + bce1(p.z, y.z) + bce1(p.w, y.w);
}

// block-reduce N doubles (shuffle + LDS), thread0 plain-stores to slot[j]
template<int N>
__device__ __forceinline__ void block_reduce_store(const double* vals, double* slot) {
    __shared__ double sm[4][N];
    const int lane = threadIdx.x & 63;
    const int wid  = threadIdx.x >> 6;
    #pragma unroll
    for (int j = 0; j < N; ++j) {
        double v = vals[j];
        #pragma unroll
        for (int o = 32; o > 0; o >>= 1)
            v += __shfl_down(v, o, 64);
        if (lane == 0) sm[wid][j] = v;
    }
    __syncthreads();
    if (threadIdx.x == 0) {
        #pragma unroll
        for (int j = 0; j < N; ++j)
            slot[j] = sm[0][j] + sm[1][j] + sm[2][j] + sm[3][j];
    }
}

// ---- fused kernel: phase A (l1+l2+mask for this block's 128 rows) then
//      phase B (level3 address-select static streaming over the same rows) ----
// Phase A: threads 0..127 each own one row (waves 0-1 active, 2-3 skip —
// uniform per-wave). Masks published via 128B LDS. Phase B: r10's proven
// shape — 2 threads/row, 8 unconditional dwordx4 per entry, per-lane
// address select (inactive -> array base, one L1-hot line), mask as
// multiplier. No contended atomics anywhere; one plain slot store per block.
__global__ void __launch_bounds__(TPB) hml_fused(
    const float* __restrict__ l1p, const float* __restrict__ l2pCC,
    const float* __restrict__ l2pURW,
    const float* __restrict__ p3a, const float* __restrict__ p3b,
    const float* __restrict__ p3c, const float* __restrict__ p3d,
    const float* __restrict__ p3e,
    const float* __restrict__ l1y, const float* __restrict__ l2yCC,
    const float* __restrict__ l2yURW,
    const float* __restrict__ y3a, const float* __restrict__ y3b,
    const float* __restrict__ y3c, const float* __restrict__ y3d,
    const float* __restrict__ y3e,
    int nrows, double* __restrict__ pAB)
{
    __shared__ unsigned char smask[ROWS_PER_B];

    double s1 = 0, s2cc = 0, s2urw = 0, nCC = 0, nURW = 0, n3 = 0, s3 = 0;

    const int rbase = blockIdx.x * ROWS_PER_B;

    // ---------- phase A ----------
    if (threadIdx.x < ROWS_PER_B) {
        const long i = rbase + threadIdx.x;
        unsigned mb = 0u;
        if (i < nrows) {
            float2 p1 = ((const float2*)l1p)[i];
            float2 y1 = ((const float2*)l1y)[i];
            float2 pu = ((const float2*)l2pURW)[i];
            float2 yu = ((const float2*)l2yURW)[i];
            float c0p = l2pCC[i*3+0], c1p = l2pCC[i*3+1], c2p = l2pCC[i*3+2];
            float c0y = l2yCC[i*3+0], c1y = l2yCC[i*3+1], c2y = l2yCC[i*3+2];

            s1 = (double)(bce1(p1.x, y1.x) + bce1(p1.y, y1.y));

            const bool aCC  = (y1.x > 0.5f);
            const bool aURW = (y1.y > 0.5f);
            const float fCC  = aCC  ? 1.f : 0.f;
            const float fURW = aURW ? 1.f : 0.f;

            s2cc  = (double)(fCC  * (bce1(c0p, c0y) + bce1(c1p, c1y) + bce1(c2p, c2y)));
            s2urw = (double)(fURW * (bce1(pu.x, yu.x) + bce1(pu.y, yu.y)));
            nCC   = (double)fCC;
            nURW  = (double)fURW;

            const unsigned b0 = (aCC  && c0y  != 0.f) ? 1u : 0u;
            const unsigned b1 = (aCC  && c1y  != 0.f) ? 1u : 0u;
            const unsigned b2 = (aCC  && c2y  != 0.f) ? 1u : 0u;
            const unsigned b3 = (aURW && yu.x != 0.f) ? 1u : 0u;
            const unsigned b4 = (aURW && yu.y != 0.f) ? 1u : 0u;
            n3 = (double)(b0 + b1 + b2 + b3 + b4);
            mb = b0 | (b1 << 1) | (b2 << 2) | (b3 << 3) | (b4 << 4);
        }
        smask[threadIdx.x] = (unsigned char)mb;
    }
    __syncthreads();

    // ---------- phase B ----------
    const int  row  = rbase + (threadIdx.x >> 1);
    const long base = (long)row * 8 + (threadIdx.x & 1) * 4;   // float4 index
    const unsigned mb = (row < nrows) ? (unsigned)smask[threadIdx.x >> 1] : 0u;

    const float4* P[5] = { (const float4*)p3a, (const float4*)p3b, (const float4*)p3c,
                           (const float4*)p3d, (const float4*)p3e };
    const float4* Q[5] = { (const float4*)y3a, (const float4*)y3b, (const float4*)y3c,
                           (const float4*)y3d, (const float4*)y3e };

    #pragma unroll
    for (int e = 0; e < 5; ++e) {
        const bool act = ((mb >> e) & 1u) != 0u;
        // address select: active -> this row's 64B half; inactive -> array base
        const float4* __restrict__ p4 = act ? (P[e] + base) : P[e];
        const float4* __restrict__ q4 = act ? (Q[e] + base) : Q[e];

        // 8 independent unconditional 16B loads, static offsets
        float4 p0 = p4[0], p1 = p4[1], p2 = p4[2], p3_ = p4[3];
        float4 q0 = q4[0], q1 = q4[1], q2 = q4[2], q3_ = q4[3];

        const float mf = act ? 1.f : 0.f;
        s3 += (double)(mf * (bce4(p0, q0) + bce4(p1, q1)
                           + bce4(p2, q2) + bce4(p3_, q3_)));
    }

    double vals[7] = { s1, s2cc, s2urw, nCC, nURW, n3, s3 };
    block_reduce_store<7>(vals, pAB + (size_t)blockIdx.x * 8);
}

// ---- final: reduce partial slots, apply formula ----
__global__ void __launch_bounds__(TPB) hml_final(
    const double* __restrict__ pAB, int nB,
    float* __restrict__ out, int nrows)
{
    double S[7] = { 0, 0, 0, 0, 0, 0, 0 };   // s1,s2cc,s2urw,nCC,nURW,n3,s3

    for (int i = threadIdx.x; i < nB; i += TPB) {
        #pragma unroll
        for (int j = 0; j < 7; ++j) S[j] += pAB[(size_t)i * 8 + j];
    }

    __shared__ double sm[4][7];
    const int lane = threadIdx.x & 63;
    const int wid  = threadIdx.x >> 6;
    #pragma unroll
    for (int j = 0; j < 7; ++j) {
        double v = S[j];
        #pragma unroll
        for (int o = 32; o > 0; o >>= 1)
            v += __shfl_down(v, o, 64);
        if (lane == 0) sm[wid][j] = v;
    }
    __syncthreads();

    if (threadIdx.x == 0) {
        double s1   = sm[0][0] + sm[1][0] + sm[2][0] + sm[3][0];
        double s2cc = sm[0][1] + sm[1][1] + sm[2][1] + sm[3][1];
        double s2u  = sm[0][2] + sm[1][2] + sm[2][2] + sm[3][2];
        double nCC  = sm[0][3] + sm[1][3] + sm[2][3] + sm[3][3];
        double nU   = sm[0][4] + sm[1][4] + sm[2][4] + sm[3][4];
        double n3   = sm[0][5] + sm[1][5] + sm[2][5] + sm[3][5];
        double s3   = sm[0][6] + sm[1][6] + sm[2][6] + sm[3][6];

        double level1 = s1 / ((double)nrows * 2.0);
        double l2 = 0.0;
        if (nCC > 0.0) l2 += s2cc / (nCC * 3.0);
        if (nU  > 0.0) l2 += s2u  / (nU  * 2.0);
        double level2 = 0.5 * l2;
        double level3 = (n3 > 0.0) ? (s3 / 32.0) / n3 : 0.0;

        out[0] = (float)(level1 + level2 + level3);
    }
}

extern "C" void kernel_launch(void* const* d_in, const int* in_sizes, int n_in,
                              void* d_out, int out_size, void* d_ws, size_t ws_size,
                              hipStream_t stream) {
    const float* l1p   = (const float*)d_in[0];
    const float* l2pCC = (const float*)d_in[1];
    const float* l2pURW= (const float*)d_in[2];
    const float* p3a   = (const float*)d_in[3];
    const float* p3b   = (const float*)d_in[4];
    const float* p3c   = (const float*)d_in[5];
    const float* p3d   = (const float*)d_in[6];
    const float* p3e   = (const float*)d_in[7];
    const float* l1y   = (const float*)d_in[8];
    const float* l2yCC = (const float*)d_in[9];
    const float* l2yURW= (const float*)d_in[10];
    const float* y3a   = (const float*)d_in[11];
    const float* y3b   = (const float*)d_in[12];
    const float* y3c   = (const float*)d_in[13];
    const float* y3d   = (const float*)d_in[14];
    const float* y3e   = (const float*)d_in[15];

    const int nrows = in_sizes[0] / 2;
    const int nB    = (nrows + ROWS_PER_B - 1) / ROWS_PER_B;   // 2048

    // ws layout: pAB = nB slots x 8 doubles (plain-stored every call; no memset)
    double* pAB = (double*)d_ws;

    hml_fused<<<nB, TPB, 0, stream>>>(
        l1p, l2pCC, l2pURW, p3a, p3b, p3c, p3d, p3e,
        l1y, l2yCC, l2yURW, y3a, y3b, y3c, y3d, y3e,
        nrows, pAB);

    hml_final<<<1, TPB, 0, stream>>>(pAB, nB, (float*)d_out, nrows);
}

// Round 12
// 32.979 us; speedup vs baseline: 1.3404x; 1.3404x over previous
//
#include <hip/hip_runtime.h>

#define TPB 256
#define ROWS_PER_B 128   // one block = 128 rows; 2 threads per row in phase B

// y is exactly 0.0f or 1.0f; -(y*log(p) + (1-y)*log1p(-p)) reduces to a select.
__device__ __forceinline__ float bce1(float p, float y) {
    return (y > 0.5f) ? -__logf(p) : -__logf(1.0f - p);
}
__device__ __forceinline__ float bce4(float4 p, float4 y) {
    return bce1(p.x, y.x) + bce1(p.y, y.y) + bce1(p.z, y.z) + bce1(p.w, y.w);
}

// block-reduce N doubles (shuffle + LDS), thread0 plain-stores to slot[j].
// Ends the source values' register lifetimes — used to free phase-A state
// before phase-B's load schedule is issued.
template<int N>
__device__ __forceinline__ void block_reduce_store(const double* vals, double* slot) {
    __shared__ double sm[4][N];
    const int lane = threadIdx.x & 63;
    const int wid  = threadIdx.x >> 6;
    #pragma unroll
    for (int j = 0; j < N; ++j) {
        double v = vals[j];
        #pragma unroll
        for (int o = 32; o > 0; o >>= 1)
            v += __shfl_down(v, o, 64);
        if (lane == 0) sm[wid][j] = v;
    }
    __syncthreads();
    if (threadIdx.x == 0) {
        #pragma unroll
        for (int j = 0; j < N; ++j)
            slot[j] = sm[0][j] + sm[1][j] + sm[2][j] + sm[3][j];
    }
}

// ---- fused kernel, register-lifetime-fixed ----
// Phase A (threads 0..127, one row each): l1+l2 BCE, n3, 5-bit mask -> LDS.
// Then IMMEDIATELY block-reduce+store the 6 phase-A values (frees registers).
// Phase B (all 256 threads, 2/row): r10's static address-select streaming,
// only s3 live; second reduce+store to slot lane 6. No contended atomics.
// __launch_bounds__(256,8): 8 waves/EU -> VGPR capped at 64 -> full occupancy.
__global__ void __launch_bounds__(TPB, 8) hml_fused(
    const float* __restrict__ l1p, const float* __restrict__ l2pCC,
    const float* __restrict__ l2pURW,
    const float* __restrict__ p3a, const float* __restrict__ p3b,
    const float* __restrict__ p3c, const float* __restrict__ p3d,
    const float* __restrict__ p3e,
    const float* __restrict__ l1y, const float* __restrict__ l2yCC,
    const float* __restrict__ l2yURW,
    const float* __restrict__ y3a, const float* __restrict__ y3b,
    const float* __restrict__ y3c, const float* __restrict__ y3d,
    const float* __restrict__ y3e,
    int nrows, double* __restrict__ pAB)
{
    __shared__ unsigned char smask[ROWS_PER_B];

    const int rbase = blockIdx.x * ROWS_PER_B;
    double* slot = pAB + (size_t)blockIdx.x * 8;

    // ---------- phase A (threads 0..127) ----------
    {
        double s1 = 0, s2cc = 0, s2urw = 0, nCC = 0, nURW = 0, n3 = 0;
        if (threadIdx.x < ROWS_PER_B) {
            const long i = rbase + threadIdx.x;
            unsigned mb = 0u;
            if (i < nrows) {
                float2 p1 = ((const float2*)l1p)[i];
                float2 y1 = ((const float2*)l1y)[i];
                float2 pu = ((const float2*)l2pURW)[i];
                float2 yu = ((const float2*)l2yURW)[i];
                float c0p = l2pCC[i*3+0], c1p = l2pCC[i*3+1], c2p = l2pCC[i*3+2];
                float c0y = l2yCC[i*3+0], c1y = l2yCC[i*3+1], c2y = l2yCC[i*3+2];

                s1 = (double)(bce1(p1.x, y1.x) + bce1(p1.y, y1.y));

                const bool aCC  = (y1.x > 0.5f);
                const bool aURW = (y1.y > 0.5f);
                const float fCC  = aCC  ? 1.f : 0.f;
                const float fURW = aURW ? 1.f : 0.f;

                s2cc  = (double)(fCC  * (bce1(c0p, c0y) + bce1(c1p, c1y) + bce1(c2p, c2y)));
                s2urw = (double)(fURW * (bce1(pu.x, yu.x) + bce1(pu.y, yu.y)));
                nCC   = (double)fCC;
                nURW  = (double)fURW;

                const unsigned b0 = (aCC  && c0y  != 0.f) ? 1u : 0u;
                const unsigned b1 = (aCC  && c1y  != 0.f) ? 1u : 0u;
                const unsigned b2 = (aCC  && c2y  != 0.f) ? 1u : 0u;
                const unsigned b3 = (aURW && yu.x != 0.f) ? 1u : 0u;
                const unsigned b4 = (aURW && yu.y != 0.f) ? 1u : 0u;
                n3 = (double)(b0 + b1 + b2 + b3 + b4);
                mb = b0 | (b1 << 1) | (b2 << 2) | (b3 << 3) | (b4 << 4);
            }
            smask[threadIdx.x] = (unsigned char)mb;
        }

        // reduce+store NOW: phase-A accumulators die here (barrier inside also
        // publishes smask for phase B)
        double vals[6] = { s1, s2cc, s2urw, nCC, nURW, n3 };
        block_reduce_store<6>(vals, slot);
    }

    // ---------- phase B (all 256 threads, only s3 live) ----------
    const int  row  = rbase + (threadIdx.x >> 1);
    const long base = (long)row * 8 + (threadIdx.x & 1) * 4;   // float4 index
    const unsigned mb = (row < nrows) ? (unsigned)smask[threadIdx.x >> 1] : 0u;

    const float4* P[5] = { (const float4*)p3a, (const float4*)p3b, (const float4*)p3c,
                           (const float4*)p3d, (const float4*)p3e };
    const float4* Q[5] = { (const float4*)y3a, (const float4*)y3b, (const float4*)y3c,
                           (const float4*)y3d, (const float4*)y3e };

    double s3 = 0;

    #pragma unroll
    for (int e = 0; e < 5; ++e) {
        const bool act = ((mb >> e) & 1u) != 0u;
        // address select: active -> this row's 64B half; inactive -> array base
        const float4* __restrict__ p4 = act ? (P[e] + base) : P[e];
        const float4* __restrict__ q4 = act ? (Q[e] + base) : Q[e];

        // 8 independent unconditional 16B loads, static offsets
        float4 p0 = p4[0], p1 = p4[1], p2 = p4[2], p3_ = p4[3];
        float4 q0 = q4[0], q1 = q4[1], q2 = q4[2], q3_ = q4[3];

        const float mf = act ? 1.f : 0.f;
        s3 += (double)(mf * (bce4(p0, q0) + bce4(p1, q1)
                           + bce4(p2, q2) + bce4(p3_, q3_)));
    }

    double vals[1] = { s3 };
    block_reduce_store<1>(vals, slot + 6);
}

// ---- final: reduce partial slots, apply formula ----
__global__ void __launch_bounds__(TPB) hml_final(
    const double* __restrict__ pAB, int nB,
    float* __restrict__ out, int nrows)
{
    double S[7] = { 0, 0, 0, 0, 0, 0, 0 };   // s1,s2cc,s2urw,nCC,nURW,n3,s3

    for (int i = threadIdx.x; i < nB; i += TPB) {
        #pragma unroll
        for (int j = 0; j < 7; ++j) S[j] += pAB[(size_t)i * 8 + j];
    }

    __shared__ double sm[4][7];
    const int lane = threadIdx.x & 63;
    const int wid  = threadIdx.x >> 6;
    #pragma unroll
    for (int j = 0; j < 7; ++j) {
        double v = S[j];
        #pragma unroll
        for (int o = 32; o > 0; o >>= 1)
            v += __shfl_down(v, o, 64);
        if (lane == 0) sm[wid][j] = v;
    }
    __syncthreads();

    if (threadIdx.x == 0) {
        double s1   = sm[0][0] + sm[1][0] + sm[2][0] + sm[3][0];
        double s2cc = sm[0][1] + sm[1][1] + sm[2][1] + sm[3][1];
        double s2u  = sm[0][2] + sm[1][2] + sm[2][2] + sm[3][2];
        double nCC  = sm[0][3] + sm[1][3] + sm[2][3] + sm[3][3];
        double nU   = sm[0][4] + sm[1][4] + sm[2][4] + sm[3][4];
        double n3   = sm[0][5] + sm[1][5] + sm[2][5] + sm[3][5];
        double s3   = sm[0][6] + sm[1][6] + sm[2][6] + sm[3][6];

        double level1 = s1 / ((double)nrows * 2.0);
        double l2 = 0.0;
        if (nCC > 0.0) l2 += s2cc / (nCC * 3.0);
        if (nU  > 0.0) l2 += s2u  / (nU  * 2.0);
        double level2 = 0.5 * l2;
        double level3 = (n3 > 0.0) ? (s3 / 32.0) / n3 : 0.0;

        out[0] = (float)(level1 + level2 + level3);
    }
}

extern "C" void kernel_launch(void* const* d_in, const int* in_sizes, int n_in,
                              void* d_out, int out_size, void* d_ws, size_t ws_size,
                              hipStream_t stream) {
    const float* l1p   = (const float*)d_in[0];
    const float* l2pCC = (const float*)d_in[1];
    const float* l2pURW= (const float*)d_in[2];
    const float* p3a   = (const float*)d_in[3];
    const float* p3b   = (const float*)d_in[4];
    const float* p3c   = (const float*)d_in[5];
    const float* p3d   = (const float*)d_in[6];
    const float* p3e   = (const float*)d_in[7];
    const float* l1y   = (const float*)d_in[8];
    const float* l2yCC = (const float*)d_in[9];
    const float* l2yURW= (const float*)d_in[10];
    const float* y3a   = (const float*)d_in[11];
    const float* y3b   = (const float*)d_in[12];
    const float* y3c   = (const float*)d_in[13];
    const float* y3d   = (const float*)d_in[14];
    const float* y3e   = (const float*)d_in[15];

    const int nrows = in_sizes[0] / 2;
    const int nB    = (nrows + ROWS_PER_B - 1) / ROWS_PER_B;   // 2048

    // ws layout: pAB = nB slots x 8 doubles (plain-stored every call; no memset)
    double* pAB = (double*)d_ws;

    hml_fused<<<nB, TPB, 0, stream>>>(
        l1p, l2pCC, l2pURW, p3a, p3b, p3c, p3d, p3e,
        l1y, l2yCC, l2yURW, y3a, y3b, y3c, y3d, y3e,
        nrows, pAB);

    hml_final<<<1, TPB, 0, stream>>>(pAB, nB, (float*)d_out, nrows);
}